// Round 6
// baseline (2219.013 us; speedup 1.0000x reference)
//
#include <hip/hip_runtime.h>
#include <hip/hip_bf16.h>

// B=2, C=128, H=W=128, K=8, STRIDE=2, DIL=2, NH=8, dh=16, HID=170, Hc=Wc=64
// Inputs fp32, output fp32 (R2/R3+R4/R5 truth table: fp32 in, fp32 out).
// ws: kcb fp32 [0, 1048576) ; vcb fp32 [1048576, 2097152)  (8 MB total)

template<int BS>
__device__ __forceinline__ float block_sum(float v, float* red){
  const int tid = threadIdx.x;
  __syncthreads();
  red[tid] = v;
  __syncthreads();
  #pragma unroll
  for(int s = BS>>1; s > 0; s >>= 1){
    if(tid < s) red[tid] += red[tid+s];
    __syncthreads();
  }
  return red[0];
}

// ---- K1: coarse-grid k,v from x (NCHW): LN1 + k/v gemv + k-LN ----
__global__ void k_kv(const float* __restrict__ x,
                     const float* __restrict__ qkv_w, const float* __restrict__ qkv_b,
                     const float* __restrict__ kg, const float* __restrict__ kb,
                     const float* __restrict__ n1g, const float* __restrict__ n1b,
                     float* __restrict__ kcb, float* __restrict__ vcb){
  __shared__ float xn[128];
  __shared__ float red[128];
  const int cp = blockIdx.x, tid = threadIdx.x;      // cp in [0, 8192)
  const int b = cp >> 12, rem = cp & 4095, ic = rem >> 6, jc = rem & 63;
  const int hw = (2*ic) * 128 + 2*jc;                // even pixel
  float xv = x[((size_t)(b*128 + tid)) * 16384 + hw];
  float mu = block_sum<128>(xv, red) * (1.f/128.f);
  float xc = xv - mu;
  float var = block_sum<128>(xc*xc, red) * (1.f/128.f);
  xn[tid] = xc * rsqrtf(var + 1e-6f) * n1g[tid] + n1b[tid];
  __syncthreads();
  const float* wk = qkv_w + (size_t)(128 + tid) * 128;
  const float* wv = qkv_w + (size_t)(256 + tid) * 128;
  float ka = qkv_b[128 + tid], va = qkv_b[256 + tid];
  for(int c = 0; c < 128; c++){ ka += xn[c] * wk[c]; va += xn[c] * wv[c]; }
  float kmu = block_sum<128>(ka, red) * (1.f/128.f);
  float kc = ka - kmu;
  float kvar = block_sum<128>(kc*kc, red) * (1.f/128.f);
  float kn = kc * rsqrtf(kvar + 1e-6f) * kg[tid] + kb[tid];
  kcb[(size_t)cp * 128 + tid] = kn;
  vcb[(size_t)cp * 128 + tid] = va;
}

// ---- K2: fused per-pixel block -> out (NCHW fp32) ----
__global__ void k_main(const float* __restrict__ x,
                       const float* __restrict__ qkv_w, const float* __restrict__ qkv_b,
                       const float* __restrict__ qg, const float* __restrict__ qb,
                       const float* __restrict__ n1g, const float* __restrict__ n1b,
                       const float* __restrict__ proj_w, const float* __restrict__ proj_b,
                       const float* __restrict__ ls1, const float* __restrict__ ls2,
                       const float* __restrict__ n2g, const float* __restrict__ n2b,
                       const float* __restrict__ fc1_w, const float* __restrict__ fc1_b,
                       const float* __restrict__ mg, const float* __restrict__ mb,
                       const float* __restrict__ fc2_w, const float* __restrict__ fc2_b,
                       const float* __restrict__ kcb, const float* __restrict__ vcb,
                       float* __restrict__ out){
  __shared__ float xn[128];
  __shared__ float qn[128];
  __shared__ float ao[128];
  __shared__ float xh[128];
  __shared__ float hs[170];
  __shared__ float red[128];
  __shared__ float sc_s[512];     // [head][64 neighbors]
  __shared__ int   cidx[64];
  const int p = blockIdx.x, tid = threadIdx.x;
  const int b = p >> 14, hw = p & 16383, h = hw >> 7, w = hw & 127;
  const int ic = h >> 1, jc = w >> 1;

  // LN1 (channel gather from NCHW)
  float xv = x[((size_t)(b*128 + tid)) * 16384 + hw];
  float mu = block_sum<128>(xv, red) * (1.f/128.f);
  float xc = xv - mu;
  float var = block_sum<128>(xc*xc, red) * (1.f/128.f);
  xn[tid] = xc * rsqrtf(var + 1e-6f) * n1g[tid] + n1b[tid];
  __syncthreads();

  // q gemv + q-LN
  {
    const float* wq = qkv_w + (size_t)tid * 128;
    float qa = qkv_b[tid];
    for(int c = 0; c < 128; c++) qa += xn[c] * wq[c];
    float qmu = block_sum<128>(qa, red) * (1.f/128.f);
    float qc = qa - qmu;
    float qvar = block_sum<128>(qc*qc, red) * (1.f/128.f);
    qn[tid] = qc * rsqrtf(qvar + 1e-6f) * qg[tid] + qb[tid];
  }
  if(tid < 64){
    const int i = tid >> 3, j = tid & 7;
    const int ri = ic + 2*i - 8, rj = jc + 2*j - 8;
    const bool valid = (ri >= 0) && (ri < 64) && (rj >= 0) && (rj < 64);
    cidx[tid] = valid ? ((b * 4096 + ri * 64 + rj) * 128) : -1;
  }
  __syncthreads();

  // scores: 8 heads x 64 neighbors, 4 per thread
  #pragma unroll
  for(int rep = 0; rep < 4; rep++){
    const int idx = rep * 128 + tid;
    const int n = idx >> 6, nb = idx & 63;
    const int ci = cidx[nb];
    float s = -1e30f;
    if(ci >= 0){
      const float* kp = kcb + ci + n * 16;
      float a = 0.f;
      #pragma unroll
      for(int d = 0; d < 16; d++) a += qn[n*16 + d] * kp[d];
      s = a * 0.25f;    // dh^-0.5
    }
    sc_s[idx] = s;
  }
  __syncthreads();

  // softmax per head (16 threads/head, 4 elems each)
  {
    const int n = tid >> 4, l = tid & 15;
    float s0 = sc_s[n*64 + l], s1 = sc_s[n*64 + l + 16];
    float s2 = sc_s[n*64 + l + 32], s3 = sc_s[n*64 + l + 48];
    float m = fmaxf(fmaxf(s0, s1), fmaxf(s2, s3));
    #pragma unroll
    for(int sft = 1; sft < 16; sft <<= 1) m = fmaxf(m, __shfl_xor(m, sft));
    float e0 = __expf(s0 - m), e1 = __expf(s1 - m);
    float e2 = __expf(s2 - m), e3 = __expf(s3 - m);
    float es = e0 + e1 + e2 + e3;
    #pragma unroll
    for(int sft = 1; sft < 16; sft <<= 1) es += __shfl_xor(es, sft);
    float inv = 1.f / es;
    sc_s[n*64 + l]      = e0 * inv;
    sc_s[n*64 + l + 16] = e1 * inv;
    sc_s[n*64 + l + 32] = e2 * inv;
    sc_s[n*64 + l + 48] = e3 * inv;
  }
  __syncthreads();

  // attention output, channel tid (head tid>>4)
  {
    const int n = tid >> 4;
    float o = 0.f;
    for(int nb = 0; nb < 64; nb++){
      const int ci = cidx[nb];
      if(ci >= 0) o += sc_s[n*64 + nb] * vcb[ci + tid];
    }
    ao[tid] = o;
  }
  __syncthreads();

  // proj + ls1*res -> xh (kept in LDS for LN2)
  {
    const float* wp = proj_w + (size_t)tid * 128;
    float acc = proj_b[tid];
    for(int c = 0; c < 128; c++) acc += ao[c] * wp[c];
    xh[tid] = xv + ls1[tid] * acc;
  }
  __syncthreads();

  // LN2
  float hxv = xh[tid];
  float mu2 = block_sum<128>(hxv, red) * (1.f/128.f);
  float xc2 = hxv - mu2;
  float var2 = block_sum<128>(xc2*xc2, red) * (1.f/128.f);
  xn[tid] = xc2 * rsqrtf(var2 + 1e-6f) * n2g[tid] + n2b[tid];
  __syncthreads();

  // fc1 (170 rows: tid, and tid+128 for tid<42) + midLN + gelu
  float hv0, hv1 = 0.f;
  {
    const float* wr = fc1_w + (size_t)tid * 128;
    float acc = fc1_b[tid];
    for(int c = 0; c < 128; c++) acc += xn[c] * wr[c];
    hv0 = acc;
    if(tid < 42){
      const float* wr2 = fc1_w + (size_t)(tid + 128) * 128;
      float acc2 = fc1_b[tid + 128];
      for(int c = 0; c < 128; c++) acc2 += xn[c] * wr2[c];
      hv1 = acc2;
    }
  }
  float hmu = block_sum<128>(hv0 + hv1, red) * (1.f/170.f);
  float d0 = hv0 - hmu;
  float d1 = (tid < 42) ? hv1 - hmu : 0.f;
  float hvar = block_sum<128>(d0*d0 + d1*d1, red) * (1.f/170.f);
  {
    float rs = rsqrtf(hvar + 1e-6f);
    float hn0 = d0 * rs * mg[tid] + mb[tid];
    float u0 = 0.7978845608028654f * (hn0 + 0.044715f * hn0*hn0*hn0);
    hs[tid] = 0.5f * hn0 * (1.f + tanhf(u0));
    if(tid < 42){
      float hn1 = d1 * rs * mg[tid + 128] + mb[tid + 128];
      float u1 = 0.7978845608028654f * (hn1 + 0.044715f * hn1*hn1*hn1);
      hs[tid + 128] = 0.5f * hn1 * (1.f + tanhf(u1));
    }
  }
  __syncthreads();

  // fc2 + ls2*res -> out (NCHW fp32, channel scatter)
  {
    const float* wr = fc2_w + (size_t)tid * 170;
    float acc = fc2_b[tid];
    for(int j = 0; j < 170; j++) acc += hs[j] * wr[j];
    out[((size_t)(b*128 + tid)) * 16384 + hw] = hxv + ls2[tid] * acc;
  }
}

extern "C" void kernel_launch(void* const* d_in, const int* in_sizes, int n_in,
                              void* d_out, int out_size, void* d_ws, size_t ws_size,
                              hipStream_t stream){
  const float* x      = (const float*)d_in[0];
  const float* qkv_w  = (const float*)d_in[1];
  const float* qkv_b  = (const float*)d_in[2];
  const float* qg     = (const float*)d_in[3];
  const float* qb     = (const float*)d_in[4];
  const float* kg     = (const float*)d_in[5];
  const float* kb     = (const float*)d_in[6];
  const float* proj_w = (const float*)d_in[7];
  const float* proj_b = (const float*)d_in[8];
  const float* n1g    = (const float*)d_in[9];
  const float* n1b    = (const float*)d_in[10];
  const float* n2g    = (const float*)d_in[11];
  const float* n2b    = (const float*)d_in[12];
  const float* ls1    = (const float*)d_in[13];
  const float* ls2    = (const float*)d_in[14];
  const float* fc1_w  = (const float*)d_in[15];
  const float* fc1_b  = (const float*)d_in[16];
  const float* mg     = (const float*)d_in[17];
  const float* mb     = (const float*)d_in[18];
  const float* fc2_w  = (const float*)d_in[19];
  const float* fc2_b  = (const float*)d_in[20];

  float* kcb = (float*)d_ws;       // 1,048,576 floats = 4 MB
  float* vcb = kcb + 1048576;      // 1,048,576 floats = 4 MB (total 8 MB)

  k_kv  <<<8192, 128, 0, stream>>>(x, qkv_w, qkv_b, kg, kb, n1g, n1b, kcb, vcb);
  k_main<<<32768, 128, 0, stream>>>(x, qkv_w, qkv_b, qg, qb, n1g, n1b,
                                    proj_w, proj_b, ls1, ls2, n2g, n2b,
                                    fc1_w, fc1_b, mg, mb, fc2_w, fc2_b,
                                    kcb, vcb, (float*)d_out);
}

// Round 7
// 470.788 us; speedup vs baseline: 4.7134x; 4.7134x over previous
//
#include <hip/hip_runtime.h>
#include <hip/hip_bf16.h>

// B=2, C=128, H=W=128, K=8, STRIDE=2, DIL=2, NH=8, dh=16, HID=170, Hc=Wc=64
// fp32 in / fp32 out (verified R6). fp32 compute throughout (same op order as R6).
// ws (floats): xt[0,4194304) ; kcb[4194304,5242880) ; vcb[5242880,6291456) ;
//   qkvT[6291456,+49152) projT[+16384) fc1T[+21760) fc2T[+21760) end 6400512 (25.6 MB)

template<int BS>
__device__ __forceinline__ float block_sum(float v, float* red){
  const int tid = threadIdx.x;
  __syncthreads();
  red[tid] = v;
  __syncthreads();
  #pragma unroll
  for(int s = BS>>1; s > 0; s >>= 1){
    if(tid < s) red[tid] += red[tid+s];
    __syncthreads();
  }
  return red[0];
}

// 4-row simultaneous block reduction (128 threads), same tree order per component
__device__ __forceinline__ float4 block_sum4(float4 v, float4* red){
  const int tid = threadIdx.x;
  __syncthreads();
  red[tid] = v;
  __syncthreads();
  #pragma unroll
  for(int s = 64; s > 0; s >>= 1){
    if(tid < s){
      float4 a = red[tid], b = red[tid+s];
      a.x += b.x; a.y += b.y; a.z += b.z; a.w += b.w;
      red[tid] = a;
    }
    __syncthreads();
  }
  return red[0];
}

// ---- K0: tiled transpose x (B,C,H,W) -> xt (B,HW,C) ----
__global__ void k_tin(const float* __restrict__ x, float* __restrict__ xt){
  __shared__ float tile[32][33];
  const int b = blockIdx.z;
  const int pb = blockIdx.x * 32;   // pixel tile
  const int cb = blockIdx.y * 32;   // channel tile
  const int tx = threadIdx.x, ty = threadIdx.y;
  #pragma unroll
  for(int r = 0; r < 32; r += 8)
    tile[ty+r][tx] = x[(size_t)(b*128 + cb+ty+r)*16384 + pb + tx];
  __syncthreads();
  #pragma unroll
  for(int r = 0; r < 32; r += 8)
    xt[(size_t)((b<<14) + pb + ty + r)*128 + cb + tx] = tile[tx][ty+r];
}

// ---- K1: weight transposes (tiny) ----
__global__ void k_wt(const float* __restrict__ qkv_w, const float* __restrict__ proj_w,
                     const float* __restrict__ fc1_w, const float* __restrict__ fc2_w,
                     float* __restrict__ qkvT, float* __restrict__ projT,
                     float* __restrict__ fc1T, float* __restrict__ fc2T){
  const int idx = blockIdx.x * 256 + threadIdx.x;
  if(idx < 49152){                        // qkvT[c*384+o] = qkv_w[o*128+c]
    const int c = idx / 384, o = idx % 384;
    qkvT[idx] = qkv_w[o*128 + c];
  } else if(idx < 65536){                 // projT[c*128+o] = proj_w[o*128+c]
    const int i = idx - 49152, c = i >> 7, o = i & 127;
    projT[i] = proj_w[o*128 + c];
  } else if(idx < 87296){                 // fc1T[c*170+o] = fc1_w[o*128+c]
    const int i = idx - 65536, c = i / 170, o = i % 170;
    fc1T[i] = fc1_w[o*128 + c];
  } else if(idx < 109056){                // fc2T[j*128+o] = fc2_w[o*170+j]
    const int i = idx - 87296, j = i >> 7, o = i & 127;
    fc2T[i] = fc2_w[o*170 + j];
  }
}

// ---- K2: coarse-grid k,v: LN1 + k/v gemv (coalesced W^T) + k-LN ----
__global__ void k_kv(const float* __restrict__ xt,
                     const float* __restrict__ qkvT, const float* __restrict__ qkv_b,
                     const float* __restrict__ kg, const float* __restrict__ kb,
                     const float* __restrict__ n1g, const float* __restrict__ n1b,
                     float* __restrict__ kcb, float* __restrict__ vcb){
  __shared__ float xn[128];
  __shared__ float red[128];
  const int cp = blockIdx.x, tid = threadIdx.x;
  const int b = cp >> 12, rem = cp & 4095, ic = rem >> 6, jc = rem & 63;
  const size_t prow = ((size_t)(b*16384 + (2*ic)*128 + 2*jc)) * 128;
  float xv = xt[prow + tid];
  float mu = block_sum<128>(xv, red) * (1.f/128.f);
  float xc = xv - mu;
  float var = block_sum<128>(xc*xc, red) * (1.f/128.f);
  xn[tid] = xc * rsqrtf(var + 1e-6f) * n1g[tid] + n1b[tid];
  __syncthreads();
  float ka = qkv_b[128 + tid], va = qkv_b[256 + tid];
  #pragma unroll 4
  for(int c = 0; c < 128; c++){
    const float xs = xn[c];
    ka += xs * qkvT[c*384 + 128 + tid];
    va += xs * qkvT[c*384 + 256 + tid];
  }
  float kmu = block_sum<128>(ka, red) * (1.f/128.f);
  float kc = ka - kmu;
  float kvar = block_sum<128>(kc*kc, red) * (1.f/128.f);
  float kn = kc * rsqrtf(kvar + 1e-6f) * kg[tid] + kb[tid];
  kcb[(size_t)cp * 128 + tid] = kn;
  vcb[(size_t)cp * 128 + tid] = va;
}

// ---- K3: per-cell (2x2 pixels) fused block, float4 register blocking ----
__global__ void __launch_bounds__(128)
k_cell(const float* __restrict__ xt_in,
       const float* __restrict__ qkvT, const float* __restrict__ qkv_b,
       const float* __restrict__ qg, const float* __restrict__ qb,
       const float* __restrict__ n1g, const float* __restrict__ n1b,
       const float* __restrict__ projT, const float* __restrict__ proj_b,
       const float* __restrict__ ls1, const float* __restrict__ ls2,
       const float* __restrict__ n2g, const float* __restrict__ n2b,
       const float* __restrict__ fc1T, const float* __restrict__ fc1_b,
       const float* __restrict__ mg, const float* __restrict__ mb,
       const float* __restrict__ fc2T, const float* __restrict__ fc2_b,
       const float* __restrict__ kcb, const float* __restrict__ vcb,
       float* __restrict__ xt_out){
  __shared__ float4 xn4[128];
  __shared__ float4 qn4[128];
  __shared__ float4 ao4[128];
  __shared__ float4 xh4[128];
  __shared__ float4 hs4[170];
  __shared__ float4 red4[128];
  __shared__ float4 sc4[512];
  __shared__ int cidx[64];
  const int cell = blockIdx.x, tid = threadIdx.x;
  const int b = cell >> 12, rem = cell & 4095, ic = rem >> 6, jc = rem & 63;
  // 4 pixel rows of the 2x2 cell: q=(s,t) -> x,y,z,w
  const size_t p0 = ((size_t)(b*16384 + (2*ic  )*128 + 2*jc  )) * 128;
  const size_t p1 = ((size_t)(b*16384 + (2*ic  )*128 + 2*jc+1)) * 128;
  const size_t p2 = ((size_t)(b*16384 + (2*ic+1)*128 + 2*jc  )) * 128;
  const size_t p3 = ((size_t)(b*16384 + (2*ic+1)*128 + 2*jc+1)) * 128;

  float4 xv;
  xv.x = xt_in[p0 + tid]; xv.y = xt_in[p1 + tid];
  xv.z = xt_in[p2 + tid]; xv.w = xt_in[p3 + tid];

  // LN1 (4 rows simultaneously)
  float4 mu = block_sum4(xv, red4);
  mu.x *= (1.f/128.f); mu.y *= (1.f/128.f); mu.z *= (1.f/128.f); mu.w *= (1.f/128.f);
  float4 xc; xc.x = xv.x-mu.x; xc.y = xv.y-mu.y; xc.z = xv.z-mu.z; xc.w = xv.w-mu.w;
  float4 sq; sq.x = xc.x*xc.x; sq.y = xc.y*xc.y; sq.z = xc.z*xc.z; sq.w = xc.w*xc.w;
  float4 var = block_sum4(sq, red4);
  float4 rs;
  rs.x = rsqrtf(var.x*(1.f/128.f) + 1e-6f); rs.y = rsqrtf(var.y*(1.f/128.f) + 1e-6f);
  rs.z = rsqrtf(var.z*(1.f/128.f) + 1e-6f); rs.w = rsqrtf(var.w*(1.f/128.f) + 1e-6f);
  {
    const float g = n1g[tid], be = n1b[tid];
    float4 t;
    t.x = xc.x*rs.x*g + be; t.y = xc.y*rs.y*g + be;
    t.z = xc.z*rs.z*g + be; t.w = xc.w*rs.w*g + be;
    xn4[tid] = t;
  }
  __syncthreads();

  // q gemv: output channel tid for 4 rows
  float4 qa;
  {
    const float bq = qkv_b[tid];
    qa.x = bq; qa.y = bq; qa.z = bq; qa.w = bq;
    #pragma unroll 4
    for(int c = 0; c < 128; c++){
      const float wv = qkvT[c*384 + tid];
      const float4 xs = xn4[c];
      qa.x += xs.x*wv; qa.y += xs.y*wv; qa.z += xs.z*wv; qa.w += xs.w*wv;
    }
  }
  // q-LN
  {
    float4 qmu = block_sum4(qa, red4);
    qmu.x *= (1.f/128.f); qmu.y *= (1.f/128.f); qmu.z *= (1.f/128.f); qmu.w *= (1.f/128.f);
    float4 qc; qc.x = qa.x-qmu.x; qc.y = qa.y-qmu.y; qc.z = qa.z-qmu.z; qc.w = qa.w-qmu.w;
    float4 qs; qs.x = qc.x*qc.x; qs.y = qc.y*qc.y; qs.z = qc.z*qc.z; qs.w = qc.w*qc.w;
    float4 qv = block_sum4(qs, red4);
    float4 qr;
    qr.x = rsqrtf(qv.x*(1.f/128.f) + 1e-6f); qr.y = rsqrtf(qv.y*(1.f/128.f) + 1e-6f);
    qr.z = rsqrtf(qv.z*(1.f/128.f) + 1e-6f); qr.w = rsqrtf(qv.w*(1.f/128.f) + 1e-6f);
    const float g = qg[tid], be = qb[tid];
    float4 t;
    t.x = qc.x*qr.x*g + be; t.y = qc.y*qr.y*g + be;
    t.z = qc.z*qr.z*g + be; t.w = qc.w*qr.w*g + be;
    qn4[tid] = t;
  }
  if(tid < 64){
    const int i = tid >> 3, j = tid & 7;
    const int ri = ic + 2*i - 8, rj = jc + 2*j - 8;
    const bool valid = (ri >= 0) && (ri < 64) && (rj >= 0) && (rj < 64);
    cidx[tid] = valid ? ((b * 4096 + ri * 64 + rj) * 128) : -1;
  }
  __syncthreads();

  // scores: idx = (head n)*64 + nb; 4 idx per thread; 4 rows per idx
  #pragma unroll
  for(int rep = 0; rep < 4; rep++){
    const int idx = rep * 128 + tid;
    const int n = idx >> 6, nb = idx & 63;
    const int ci = cidx[nb];
    float4 s;
    s.x = -1e30f; s.y = -1e30f; s.z = -1e30f; s.w = -1e30f;
    if(ci >= 0){
      const float* kp = kcb + ci + n * 16;
      float4 a; a.x = 0.f; a.y = 0.f; a.z = 0.f; a.w = 0.f;
      #pragma unroll
      for(int d = 0; d < 16; d++){
        const float kvv = kp[d];
        const float4 qq = qn4[n*16 + d];
        a.x += qq.x*kvv; a.y += qq.y*kvv; a.z += qq.z*kvv; a.w += qq.w*kvv;
      }
      s.x = a.x*0.25f; s.y = a.y*0.25f; s.z = a.z*0.25f; s.w = a.w*0.25f;
    }
    sc4[idx] = s;
  }
  __syncthreads();

  // softmax per head (16 threads/head, 4 nb each, 4 rows componentwise)
  {
    const int n = tid >> 4, l = tid & 15;
    float4 s0 = sc4[n*64 + l], s1 = sc4[n*64 + l + 16];
    float4 s2 = sc4[n*64 + l + 32], s3 = sc4[n*64 + l + 48];
    float4 m;
    m.x = fmaxf(fmaxf(s0.x,s1.x), fmaxf(s2.x,s3.x));
    m.y = fmaxf(fmaxf(s0.y,s1.y), fmaxf(s2.y,s3.y));
    m.z = fmaxf(fmaxf(s0.z,s1.z), fmaxf(s2.z,s3.z));
    m.w = fmaxf(fmaxf(s0.w,s1.w), fmaxf(s2.w,s3.w));
    #pragma unroll
    for(int sft = 1; sft < 16; sft <<= 1){
      m.x = fmaxf(m.x, __shfl_xor(m.x, sft));
      m.y = fmaxf(m.y, __shfl_xor(m.y, sft));
      m.z = fmaxf(m.z, __shfl_xor(m.z, sft));
      m.w = fmaxf(m.w, __shfl_xor(m.w, sft));
    }
    float4 e0, e1, e2, e3, es;
    e0.x = __expf(s0.x-m.x); e0.y = __expf(s0.y-m.y); e0.z = __expf(s0.z-m.z); e0.w = __expf(s0.w-m.w);
    e1.x = __expf(s1.x-m.x); e1.y = __expf(s1.y-m.y); e1.z = __expf(s1.z-m.z); e1.w = __expf(s1.w-m.w);
    e2.x = __expf(s2.x-m.x); e2.y = __expf(s2.y-m.y); e2.z = __expf(s2.z-m.z); e2.w = __expf(s2.w-m.w);
    e3.x = __expf(s3.x-m.x); e3.y = __expf(s3.y-m.y); e3.z = __expf(s3.z-m.z); e3.w = __expf(s3.w-m.w);
    es.x = e0.x+e1.x+e2.x+e3.x; es.y = e0.y+e1.y+e2.y+e3.y;
    es.z = e0.z+e1.z+e2.z+e3.z; es.w = e0.w+e1.w+e2.w+e3.w;
    #pragma unroll
    for(int sft = 1; sft < 16; sft <<= 1){
      es.x += __shfl_xor(es.x, sft); es.y += __shfl_xor(es.y, sft);
      es.z += __shfl_xor(es.z, sft); es.w += __shfl_xor(es.w, sft);
    }
    float4 inv;
    inv.x = 1.f/es.x; inv.y = 1.f/es.y; inv.z = 1.f/es.z; inv.w = 1.f/es.w;
    float4 o;
    o.x = e0.x*inv.x; o.y = e0.y*inv.y; o.z = e0.z*inv.z; o.w = e0.w*inv.w; sc4[n*64+l] = o;
    o.x = e1.x*inv.x; o.y = e1.y*inv.y; o.z = e1.z*inv.z; o.w = e1.w*inv.w; sc4[n*64+l+16] = o;
    o.x = e2.x*inv.x; o.y = e2.y*inv.y; o.z = e2.z*inv.z; o.w = e2.w*inv.w; sc4[n*64+l+32] = o;
    o.x = e3.x*inv.x; o.y = e3.y*inv.y; o.z = e3.z*inv.z; o.w = e3.w*inv.w; sc4[n*64+l+48] = o;
  }
  __syncthreads();

  // PV: channel tid (head tid>>4), one coalesced v load reused by 4 rows
  {
    const int n = tid >> 4;
    float4 o; o.x = 0.f; o.y = 0.f; o.z = 0.f; o.w = 0.f;
    for(int nb = 0; nb < 64; nb++){
      const int ci = cidx[nb];
      if(ci >= 0){
        const float vv = vcb[ci + tid];
        const float4 pr = sc4[n*64 + nb];
        o.x += pr.x*vv; o.y += pr.y*vv; o.z += pr.z*vv; o.w += pr.w*vv;
      }
    }
    ao4[tid] = o;
  }
  __syncthreads();

  // proj + ls1*res
  float4 xh;
  {
    const float bp = proj_b[tid];
    float4 acc; acc.x = bp; acc.y = bp; acc.z = bp; acc.w = bp;
    #pragma unroll 4
    for(int c = 0; c < 128; c++){
      const float wv = projT[c*128 + tid];
      const float4 a = ao4[c];
      acc.x += a.x*wv; acc.y += a.y*wv; acc.z += a.z*wv; acc.w += a.w*wv;
    }
    const float l1 = ls1[tid];
    xh.x = xv.x + l1*acc.x; xh.y = xv.y + l1*acc.y;
    xh.z = xv.z + l1*acc.z; xh.w = xv.w + l1*acc.w;
    xh4[tid] = xh;
  }

  // LN2
  {
    float4 mu2 = block_sum4(xh, red4);
    mu2.x *= (1.f/128.f); mu2.y *= (1.f/128.f); mu2.z *= (1.f/128.f); mu2.w *= (1.f/128.f);
    float4 c2; c2.x = xh.x-mu2.x; c2.y = xh.y-mu2.y; c2.z = xh.z-mu2.z; c2.w = xh.w-mu2.w;
    float4 s2; s2.x = c2.x*c2.x; s2.y = c2.y*c2.y; s2.z = c2.z*c2.z; s2.w = c2.w*c2.w;
    float4 v2 = block_sum4(s2, red4);
    float4 r2;
    r2.x = rsqrtf(v2.x*(1.f/128.f) + 1e-6f); r2.y = rsqrtf(v2.y*(1.f/128.f) + 1e-6f);
    r2.z = rsqrtf(v2.z*(1.f/128.f) + 1e-6f); r2.w = rsqrtf(v2.w*(1.f/128.f) + 1e-6f);
    const float g = n2g[tid], be = n2b[tid];
    float4 t;
    t.x = c2.x*r2.x*g + be; t.y = c2.y*r2.y*g + be;
    t.z = c2.z*r2.z*g + be; t.w = c2.w*r2.w*g + be;
    xn4[tid] = t;
  }
  __syncthreads();

  // fc1 (rows tid, tid+128 for tid<42) + midLN + gelu
  float4 hv0, hv1;
  {
    const float b0 = fc1_b[tid];
    hv0.x = b0; hv0.y = b0; hv0.z = b0; hv0.w = b0;
    hv1.x = 0.f; hv1.y = 0.f; hv1.z = 0.f; hv1.w = 0.f;
    if(tid < 42){
      const float b1 = fc1_b[tid + 128];
      hv1.x = b1; hv1.y = b1; hv1.z = b1; hv1.w = b1;
    }
    #pragma unroll 4
    for(int c = 0; c < 128; c++){
      const float4 xs = xn4[c];
      const float w0 = fc1T[c*170 + tid];
      hv0.x += xs.x*w0; hv0.y += xs.y*w0; hv0.z += xs.z*w0; hv0.w += xs.w*w0;
      if(tid < 42){
        const float w1 = fc1T[c*170 + tid + 128];
        hv1.x += xs.x*w1; hv1.y += xs.y*w1; hv1.z += xs.z*w1; hv1.w += xs.w*w1;
      }
    }
  }
  {
    float4 sum01;
    sum01.x = hv0.x + hv1.x; sum01.y = hv0.y + hv1.y;
    sum01.z = hv0.z + hv1.z; sum01.w = hv0.w + hv1.w;
    float4 hmu = block_sum4(sum01, red4);
    hmu.x *= (1.f/170.f); hmu.y *= (1.f/170.f); hmu.z *= (1.f/170.f); hmu.w *= (1.f/170.f);
    float4 d0, d1;
    d0.x = hv0.x-hmu.x; d0.y = hv0.y-hmu.y; d0.z = hv0.z-hmu.z; d0.w = hv0.w-hmu.w;
    if(tid < 42){
      d1.x = hv1.x-hmu.x; d1.y = hv1.y-hmu.y; d1.z = hv1.z-hmu.z; d1.w = hv1.w-hmu.w;
    } else { d1.x = 0.f; d1.y = 0.f; d1.z = 0.f; d1.w = 0.f; }
    float4 ssq;
    ssq.x = d0.x*d0.x + d1.x*d1.x; ssq.y = d0.y*d0.y + d1.y*d1.y;
    ssq.z = d0.z*d0.z + d1.z*d1.z; ssq.w = d0.w*d0.w + d1.w*d1.w;
    float4 hvr = block_sum4(ssq, red4);
    float4 hrs;
    hrs.x = rsqrtf(hvr.x*(1.f/170.f) + 1e-6f); hrs.y = rsqrtf(hvr.y*(1.f/170.f) + 1e-6f);
    hrs.z = rsqrtf(hvr.z*(1.f/170.f) + 1e-6f); hrs.w = rsqrtf(hvr.w*(1.f/170.f) + 1e-6f);
    {
      const float g = mg[tid], be = mb[tid];
      float4 hn, gl;
      hn.x = d0.x*hrs.x*g + be; hn.y = d0.y*hrs.y*g + be;
      hn.z = d0.z*hrs.z*g + be; hn.w = d0.w*hrs.w*g + be;
      const float kA = 0.7978845608028654f, kB = 0.044715f;
      gl.x = 0.5f*hn.x*(1.f + tanhf(kA*(hn.x + kB*hn.x*hn.x*hn.x)));
      gl.y = 0.5f*hn.y*(1.f + tanhf(kA*(hn.y + kB*hn.y*hn.y*hn.y)));
      gl.z = 0.5f*hn.z*(1.f + tanhf(kA*(hn.z + kB*hn.z*hn.z*hn.z)));
      gl.w = 0.5f*hn.w*(1.f + tanhf(kA*(hn.w + kB*hn.w*hn.w*hn.w)));
      hs4[tid] = gl;
    }
    if(tid < 42){
      const float g = mg[tid + 128], be = mb[tid + 128];
      float4 hn, gl;
      hn.x = d1.x*hrs.x*g + be; hn.y = d1.y*hrs.y*g + be;
      hn.z = d1.z*hrs.z*g + be; hn.w = d1.w*hrs.w*g + be;
      const float kA = 0.7978845608028654f, kB = 0.044715f;
      gl.x = 0.5f*hn.x*(1.f + tanhf(kA*(hn.x + kB*hn.x*hn.x*hn.x)));
      gl.y = 0.5f*hn.y*(1.f + tanhf(kA*(hn.y + kB*hn.y*hn.y*hn.y)));
      gl.z = 0.5f*hn.z*(1.f + tanhf(kA*(hn.z + kB*hn.z*hn.z*hn.z)));
      gl.w = 0.5f*hn.w*(1.f + tanhf(kA*(hn.w + kB*hn.w*hn.w*hn.w)));
      hs4[tid + 128] = gl;
    }
  }
  __syncthreads();

  // fc2 + ls2*res -> xt (in-place rows)
  {
    const float bf = fc2_b[tid];
    float4 acc; acc.x = bf; acc.y = bf; acc.z = bf; acc.w = bf;
    #pragma unroll 2
    for(int j = 0; j < 170; j++){
      const float wv = fc2T[j*128 + tid];
      const float4 hh = hs4[j];
      acc.x += hh.x*wv; acc.y += hh.y*wv; acc.z += hh.z*wv; acc.w += hh.w*wv;
    }
    const float l2 = ls2[tid];
    xt_out[p0 + tid] = xh.x + l2*acc.x;
    xt_out[p1 + tid] = xh.y + l2*acc.y;
    xt_out[p2 + tid] = xh.z + l2*acc.z;
    xt_out[p3 + tid] = xh.w + l2*acc.w;
  }
}

// ---- K4: tiled transpose xt (B,HW,C) -> out (B,C,H,W) fp32 ----
__global__ void k_tout(const float* __restrict__ xt, float* __restrict__ out){
  __shared__ float tile[32][33];
  const int b = blockIdx.z;
  const int pb = blockIdx.x * 32;
  const int cb = blockIdx.y * 32;
  const int tx = threadIdx.x, ty = threadIdx.y;
  #pragma unroll
  for(int r = 0; r < 32; r += 8)
    tile[ty+r][tx] = xt[(size_t)((b<<14) + pb + ty + r)*128 + cb + tx];
  __syncthreads();
  #pragma unroll
  for(int r = 0; r < 32; r += 8)
    out[(size_t)(b*128 + cb + ty + r)*16384 + pb + tx] = tile[tx][ty+r];
}

extern "C" void kernel_launch(void* const* d_in, const int* in_sizes, int n_in,
                              void* d_out, int out_size, void* d_ws, size_t ws_size,
                              hipStream_t stream){
  const float* x      = (const float*)d_in[0];
  const float* qkv_w  = (const float*)d_in[1];
  const float* qkv_b  = (const float*)d_in[2];
  const float* qg     = (const float*)d_in[3];
  const float* qb     = (const float*)d_in[4];
  const float* kg     = (const float*)d_in[5];
  const float* kb     = (const float*)d_in[6];
  const float* proj_w = (const float*)d_in[7];
  const float* proj_b = (const float*)d_in[8];
  const float* n1g    = (const float*)d_in[9];
  const float* n1b    = (const float*)d_in[10];
  const float* n2g    = (const float*)d_in[11];
  const float* n2b    = (const float*)d_in[12];
  const float* ls1    = (const float*)d_in[13];
  const float* ls2    = (const float*)d_in[14];
  const float* fc1_w  = (const float*)d_in[15];
  const float* fc1_b  = (const float*)d_in[16];
  const float* mg     = (const float*)d_in[17];
  const float* mb     = (const float*)d_in[18];
  const float* fc2_w  = (const float*)d_in[19];
  const float* fc2_b  = (const float*)d_in[20];

  float* ws   = (float*)d_ws;
  float* xt   = ws;                  // 4,194,304
  float* kcb  = ws + 4194304;        // 1,048,576
  float* vcb  = ws + 5242880;        // 1,048,576
  float* qkvT = ws + 6291456;        // 49,152
  float* projT= ws + 6340608;        // 16,384
  float* fc1T = ws + 6356992;        // 21,760
  float* fc2T = ws + 6378752;        // 21,760  (end 6,400,512 = 25.6 MB)

  dim3 tgrid(512, 4, 2), tblk(32, 8);
  k_tin <<<tgrid, tblk, 0, stream>>>(x, xt);
  k_wt  <<<426, 256, 0, stream>>>(qkv_w, proj_w, fc1_w, fc2_w, qkvT, projT, fc1T, fc2T);
  k_kv  <<<8192, 128, 0, stream>>>(xt, qkvT, qkv_b, kg, kb, n1g, n1b, kcb, vcb);
  k_cell<<<8192, 128, 0, stream>>>(xt, qkvT, qkv_b, qg, qb, n1g, n1b,
                                   projT, proj_b, ls1, ls2, n2g, n2b,
                                   fc1T, fc1_b, mg, mb, fc2T, fc2_b,
                                   kcb, vcb, xt);
  k_tout<<<tgrid, tblk, 0, stream>>>(xt, (float*)d_out);
}

// Round 8
// 419.822 us; speedup vs baseline: 5.2856x; 1.1214x over previous
//
#include <hip/hip_runtime.h>
#include <hip/hip_bf16.h>

// B=2, C=128, H=W=128, K=8, STRIDE=2, DIL=2, NH=8, dh=16, HID=170, Hc=Wc=64
// fp32 in / fp32 out. fp32 compute, same per-output op order as R7.
// ws (floats): xt[0,4194304) kcb[4194304,+1048576) vcb[5242880,+1048576)
//   qkvT[6291456,+49152) projT[+16384) fc1T[+21760) fc2T[+21760) end 6400512 (25.6 MB)

// ---- group reductions: wave butterfly + cross-wave LDS combine ----
// 128-thread version (k_cell): 8 components (8 pixel rows)
__device__ __forceinline__ void gsum8(float v[8], float* red){
  #pragma unroll
  for(int s = 1; s < 64; s <<= 1){
    #pragma unroll
    for(int i = 0; i < 8; i++) v[i] += __shfl_xor(v[i], s);
  }
  const int wid = threadIdx.x >> 6;
  __syncthreads();
  if((threadIdx.x & 63) == 0){
    #pragma unroll
    for(int i = 0; i < 8; i++) red[wid*8 + i] = v[i];
  }
  __syncthreads();
  #pragma unroll
  for(int i = 0; i < 8; i++) v[i] = red[i] + red[8 + i];
}

// 256-thread version (k_kv): reduce over the 128 threads sharing s = tid>>7
__device__ __forceinline__ void gsum4g(float v[4], float* red){
  #pragma unroll
  for(int s = 1; s < 64; s <<= 1){
    #pragma unroll
    for(int i = 0; i < 4; i++) v[i] += __shfl_xor(v[i], s);
  }
  const int wid = threadIdx.x >> 6;       // 0..3
  const int grp = wid >> 1;               // 0,1
  __syncthreads();
  if((threadIdx.x & 63) == 0){
    #pragma unroll
    for(int i = 0; i < 4; i++) red[wid*4 + i] = v[i];
  }
  __syncthreads();
  #pragma unroll
  for(int i = 0; i < 4; i++) v[i] = red[(2*grp)*4 + i] + red[(2*grp+1)*4 + i];
}

// ---- K0: tiled transpose x (B,C,H,W) -> xt (B,HW,C) ----
__global__ void k_tin(const float* __restrict__ x, float* __restrict__ xt){
  __shared__ float tile[32][33];
  const int b = blockIdx.z;
  const int pb = blockIdx.x * 32;
  const int cb = blockIdx.y * 32;
  const int tx = threadIdx.x, ty = threadIdx.y;
  #pragma unroll
  for(int r = 0; r < 32; r += 8)
    tile[ty+r][tx] = x[(size_t)(b*128 + cb+ty+r)*16384 + pb + tx];
  __syncthreads();
  #pragma unroll
  for(int r = 0; r < 32; r += 8)
    xt[(size_t)((b<<14) + pb + ty + r)*128 + cb + tx] = tile[tx][ty+r];
}

// ---- K1: weight transposes ----
__global__ void k_wt(const float* __restrict__ qkv_w, const float* __restrict__ proj_w,
                     const float* __restrict__ fc1_w, const float* __restrict__ fc2_w,
                     float* __restrict__ qkvT, float* __restrict__ projT,
                     float* __restrict__ fc1T, float* __restrict__ fc2T){
  const int idx = blockIdx.x * 256 + threadIdx.x;
  if(idx < 49152){
    const int c = idx / 384, o = idx % 384;
    qkvT[idx] = qkv_w[o*128 + c];
  } else if(idx < 65536){
    const int i = idx - 49152, c = i >> 7, o = i & 127;
    projT[i] = proj_w[o*128 + c];
  } else if(idx < 87296){
    const int i = idx - 65536, c = i / 170, o = i % 170;
    fc1T[i] = fc1_w[o*128 + c];
  } else if(idx < 109056){
    const int i = idx - 87296, j = i >> 7, o = i & 127;
    fc2T[i] = fc2_w[o*170 + j];
  }
}

// ---- K2: coarse k,v — 256 threads, 8 coarse px/block, 4 rows/thread ----
__global__ void __launch_bounds__(256)
k_kv(const float* __restrict__ xt,
     const float* __restrict__ qkvT, const float* __restrict__ qkv_b,
     const float* __restrict__ kg, const float* __restrict__ kb,
     const float* __restrict__ n1g, const float* __restrict__ n1b,
     float* __restrict__ kcb, float* __restrict__ vcb){
  __shared__ float4 xn4[2][128];
  __shared__ float red[16];
  const int tid = threadIdx.x;
  const int c = tid & 127, s = tid >> 7;
  const int bx = blockIdx.x;                 // 1024 blocks
  size_t prow[4];
  int cpr[4];
  float xv[4];
  #pragma unroll
  for(int r = 0; r < 4; r++){
    const int cp = bx*8 + s*4 + r;
    cpr[r] = cp;
    const int b = cp >> 12, rm = cp & 4095, ic = rm >> 6, jc = rm & 63;
    prow[r] = ((size_t)(b*16384 + (2*ic)*128 + 2*jc)) * 128;
    xv[r] = xt[prow[r] + c];
  }
  // LN1 per row (reduce over channels within s-group)
  float v[4] = {xv[0], xv[1], xv[2], xv[3]};
  gsum4g(v, red);
  float xc[4], sq[4];
  #pragma unroll
  for(int r = 0; r < 4; r++){ xc[r] = xv[r] - v[r]*(1.f/128.f); sq[r] = xc[r]*xc[r]; }
  gsum4g(sq, red);
  {
    const float g = n1g[c], be = n1b[c];
    float4 t;
    t.x = xc[0]*rsqrtf(sq[0]*(1.f/128.f)+1e-6f)*g + be;
    t.y = xc[1]*rsqrtf(sq[1]*(1.f/128.f)+1e-6f)*g + be;
    t.z = xc[2]*rsqrtf(sq[2]*(1.f/128.f)+1e-6f)*g + be;
    t.w = xc[3]*rsqrtf(sq[3]*(1.f/128.f)+1e-6f)*g + be;
    xn4[s][c] = t;
  }
  __syncthreads();
  // k/v gemv
  float ka[4], va[4];
  {
    const float bk = qkv_b[128 + c], bv = qkv_b[256 + c];
    #pragma unroll
    for(int r = 0; r < 4; r++){ ka[r] = bk; va[r] = bv; }
    #pragma unroll 4
    for(int c2 = 0; c2 < 128; c2++){
      const float4 xs = xn4[s][c2];
      const float wk = qkvT[c2*384 + 128 + c];
      const float wv = qkvT[c2*384 + 256 + c];
      ka[0] += xs.x*wk; ka[1] += xs.y*wk; ka[2] += xs.z*wk; ka[3] += xs.w*wk;
      va[0] += xs.x*wv; va[1] += xs.y*wv; va[2] += xs.z*wv; va[3] += xs.w*wv;
    }
  }
  // k-LN
  float kv2[4] = {ka[0], ka[1], ka[2], ka[3]};
  gsum4g(kv2, red);
  float kc[4], ks[4];
  #pragma unroll
  for(int r = 0; r < 4; r++){ kc[r] = ka[r] - kv2[r]*(1.f/128.f); ks[r] = kc[r]*kc[r]; }
  gsum4g(ks, red);
  {
    const float g = kg[c], be = kb[c];
    #pragma unroll
    for(int r = 0; r < 4; r++){
      const float kn = kc[r]*rsqrtf(ks[r]*(1.f/128.f)+1e-6f)*g + be;
      kcb[(size_t)cpr[r]*128 + c] = kn;
      vcb[(size_t)cpr[r]*128 + c] = va[r];
    }
  }
}

// ---- K3: fused per-2-cells (8 pixels) block ----
__global__ void __launch_bounds__(128)
k_cell(const float* __restrict__ xt_in,
       const float* __restrict__ qkvT, const float* __restrict__ qkv_b,
       const float* __restrict__ qg, const float* __restrict__ qb,
       const float* __restrict__ n1g, const float* __restrict__ n1b,
       const float* __restrict__ projT, const float* __restrict__ proj_b,
       const float* __restrict__ ls1, const float* __restrict__ ls2,
       const float* __restrict__ n2g, const float* __restrict__ n2b,
       const float* __restrict__ fc1T, const float* __restrict__ fc1_b,
       const float* __restrict__ mg, const float* __restrict__ mb,
       const float* __restrict__ fc2T, const float* __restrict__ fc2_b,
       const float* __restrict__ kcb, const float* __restrict__ vcb,
       float* __restrict__ xt_out){
  __shared__ float4 xnA[128], xnB[128];
  __shared__ float4 qnA[128], qnB[128];
  __shared__ float4 aoA[128], aoB[128];
  __shared__ float4 hsA[170], hsB[170];
  __shared__ float4 sc4[512];
  __shared__ int cidxA[64], cidxB[64];
  __shared__ float red[16];
  const int tid = threadIdx.x;
  const int bx = blockIdx.x;                 // 4096 blocks
  const int b = bx >> 11, rem = bx & 2047, ip = rem >> 6, jc = rem & 63;
  const int icA = 2*ip, icB = 2*ip + 1;
  const size_t base = (size_t)b * 16384 * 128;
  size_t p[8];
  #pragma unroll
  for(int r = 0; r < 8; r++){
    const int h = 4*ip + (r >> 1) + ((r >= 4) ? 0 : 0); // placeholder, fixed below
    p[r] = 0;
  }
  // rows: cell A -> (4ip, 2jc),(4ip,2jc+1),(4ip+1,2jc),(4ip+1,2jc+1); cell B rows 4ip+2,4ip+3
  {
    const int h0 = 4*ip;
    p[0] = base + ((size_t)(h0*128     + 2*jc    ))*128;
    p[1] = base + ((size_t)(h0*128     + 2*jc + 1))*128;
    p[2] = base + ((size_t)((h0+1)*128 + 2*jc    ))*128;
    p[3] = base + ((size_t)((h0+1)*128 + 2*jc + 1))*128;
    p[4] = base + ((size_t)((h0+2)*128 + 2*jc    ))*128;
    p[5] = base + ((size_t)((h0+2)*128 + 2*jc + 1))*128;
    p[6] = base + ((size_t)((h0+3)*128 + 2*jc    ))*128;
    p[7] = base + ((size_t)((h0+3)*128 + 2*jc + 1))*128;
  }
  float xv[8];
  #pragma unroll
  for(int r = 0; r < 8; r++) xv[r] = xt_in[p[r] + tid];

  // ---- LN1 (8 rows) ----
  float v[8];
  #pragma unroll
  for(int r = 0; r < 8; r++) v[r] = xv[r];
  gsum8(v, red);
  float xc[8], sq[8];
  #pragma unroll
  for(int r = 0; r < 8; r++){ xc[r] = xv[r] - v[r]*(1.f/128.f); sq[r] = xc[r]*xc[r]; }
  gsum8(sq, red);
  {
    const float g = n1g[tid], be = n1b[tid];
    float4 a, bb;
    a.x  = xc[0]*rsqrtf(sq[0]*(1.f/128.f)+1e-6f)*g + be;
    a.y  = xc[1]*rsqrtf(sq[1]*(1.f/128.f)+1e-6f)*g + be;
    a.z  = xc[2]*rsqrtf(sq[2]*(1.f/128.f)+1e-6f)*g + be;
    a.w  = xc[3]*rsqrtf(sq[3]*(1.f/128.f)+1e-6f)*g + be;
    bb.x = xc[4]*rsqrtf(sq[4]*(1.f/128.f)+1e-6f)*g + be;
    bb.y = xc[5]*rsqrtf(sq[5]*(1.f/128.f)+1e-6f)*g + be;
    bb.z = xc[6]*rsqrtf(sq[6]*(1.f/128.f)+1e-6f)*g + be;
    bb.w = xc[7]*rsqrtf(sq[7]*(1.f/128.f)+1e-6f)*g + be;
    xnA[tid] = a; xnB[tid] = bb;
  }
  __syncthreads();

  // ---- q gemv (8 rows) ----
  float qa[8];
  {
    const float bq = qkv_b[tid];
    #pragma unroll
    for(int r = 0; r < 8; r++) qa[r] = bq;
    #pragma unroll 4
    for(int c = 0; c < 128; c++){
      const float w = qkvT[c*384 + tid];
      const float4 xa = xnA[c], xb = xnB[c];
      qa[0] += xa.x*w; qa[1] += xa.y*w; qa[2] += xa.z*w; qa[3] += xa.w*w;
      qa[4] += xb.x*w; qa[5] += xb.y*w; qa[6] += xb.z*w; qa[7] += xb.w*w;
    }
  }
  // q-LN
  #pragma unroll
  for(int r = 0; r < 8; r++) v[r] = qa[r];
  gsum8(v, red);
  float qc[8], qs[8];
  #pragma unroll
  for(int r = 0; r < 8; r++){ qc[r] = qa[r] - v[r]*(1.f/128.f); qs[r] = qc[r]*qc[r]; }
  gsum8(qs, red);
  {
    const float g = qg[tid], be = qb[tid];
    float4 a, bb;
    a.x  = qc[0]*rsqrtf(qs[0]*(1.f/128.f)+1e-6f)*g + be;
    a.y  = qc[1]*rsqrtf(qs[1]*(1.f/128.f)+1e-6f)*g + be;
    a.z  = qc[2]*rsqrtf(qs[2]*(1.f/128.f)+1e-6f)*g + be;
    a.w  = qc[3]*rsqrtf(qs[3]*(1.f/128.f)+1e-6f)*g + be;
    bb.x = qc[4]*rsqrtf(qs[4]*(1.f/128.f)+1e-6f)*g + be;
    bb.y = qc[5]*rsqrtf(qs[5]*(1.f/128.f)+1e-6f)*g + be;
    bb.z = qc[6]*rsqrtf(qs[6]*(1.f/128.f)+1e-6f)*g + be;
    bb.w = qc[7]*rsqrtf(qs[7]*(1.f/128.f)+1e-6f)*g + be;
    qnA[tid] = a; qnB[tid] = bb;
  }
  if(tid < 64){
    const int i = tid >> 3, j = tid & 7;
    const int rj = jc + 2*j - 8;
    const bool vj = (rj >= 0) && (rj < 64);
    const int riA = icA + 2*i - 8, riB = icB + 2*i - 8;
    cidxA[tid] = (vj && riA >= 0 && riA < 64) ? ((b*4096 + riA*64 + rj)*128) : -1;
    cidxB[tid] = (vj && riB >= 0 && riB < 64) ? ((b*4096 + riB*64 + rj)*128) : -1;
  }
  __syncthreads();

  // ---- attention: cell A then cell B (sc4 reused) ----
  float4 oA, oB;
  for(int cell = 0; cell < 2; cell++){
    const int* cidx = cell ? cidxB : cidxA;
    // scores
    #pragma unroll
    for(int rep = 0; rep < 4; rep++){
      const int idx = rep*128 + tid;
      const int n = idx >> 6, nb = idx & 63;
      const int ci = cidx[nb];
      float4 s; s.x = -1e30f; s.y = -1e30f; s.z = -1e30f; s.w = -1e30f;
      if(ci >= 0){
        const float* kp = kcb + ci + n*16;
        float4 a; a.x = 0.f; a.y = 0.f; a.z = 0.f; a.w = 0.f;
        #pragma unroll
        for(int d = 0; d < 16; d++){
          const float kvv = kp[d];
          const float4 qq = cell ? qnB[n*16 + d] : qnA[n*16 + d];
          a.x += qq.x*kvv; a.y += qq.y*kvv; a.z += qq.z*kvv; a.w += qq.w*kvv;
        }
        s.x = a.x*0.25f; s.y = a.y*0.25f; s.z = a.z*0.25f; s.w = a.w*0.25f;
      }
      sc4[idx] = s;
    }
    __syncthreads();
    // softmax (per head, 16 lanes x 4 nb)
    {
      const int n = tid >> 4, l = tid & 15;
      float4 s0 = sc4[n*64 + l], s1 = sc4[n*64 + l + 16];
      float4 s2 = sc4[n*64 + l + 32], s3 = sc4[n*64 + l + 48];
      float4 m;
      m.x = fmaxf(fmaxf(s0.x,s1.x), fmaxf(s2.x,s3.x));
      m.y = fmaxf(fmaxf(s0.y,s1.y), fmaxf(s2.y,s3.y));
      m.z = fmaxf(fmaxf(s0.z,s1.z), fmaxf(s2.z,s3.z));
      m.w = fmaxf(fmaxf(s0.w,s1.w), fmaxf(s2.w,s3.w));
      #pragma unroll
      for(int sft = 1; sft < 16; sft <<= 1){
        m.x = fmaxf(m.x, __shfl_xor(m.x, sft));
        m.y = fmaxf(m.y, __shfl_xor(m.y, sft));
        m.z = fmaxf(m.z, __shfl_xor(m.z, sft));
        m.w = fmaxf(m.w, __shfl_xor(m.w, sft));
      }
      float4 e0, e1, e2, e3, es;
      e0.x = __expf(s0.x-m.x); e0.y = __expf(s0.y-m.y); e0.z = __expf(s0.z-m.z); e0.w = __expf(s0.w-m.w);
      e1.x = __expf(s1.x-m.x); e1.y = __expf(s1.y-m.y); e1.z = __expf(s1.z-m.z); e1.w = __expf(s1.w-m.w);
      e2.x = __expf(s2.x-m.x); e2.y = __expf(s2.y-m.y); e2.z = __expf(s2.z-m.z); e2.w = __expf(s2.w-m.w);
      e3.x = __expf(s3.x-m.x); e3.y = __expf(s3.y-m.y); e3.z = __expf(s3.z-m.z); e3.w = __expf(s3.w-m.w);
      es.x = e0.x+e1.x+e2.x+e3.x; es.y = e0.y+e1.y+e2.y+e3.y;
      es.z = e0.z+e1.z+e2.z+e3.z; es.w = e0.w+e1.w+e2.w+e3.w;
      #pragma unroll
      for(int sft = 1; sft < 16; sft <<= 1){
        es.x += __shfl_xor(es.x, sft); es.y += __shfl_xor(es.y, sft);
        es.z += __shfl_xor(es.z, sft); es.w += __shfl_xor(es.w, sft);
      }
      float4 inv; inv.x = 1.f/es.x; inv.y = 1.f/es.y; inv.z = 1.f/es.z; inv.w = 1.f/es.w;
      float4 o;
      o.x = e0.x*inv.x; o.y = e0.y*inv.y; o.z = e0.z*inv.z; o.w = e0.w*inv.w; sc4[n*64+l]    = o;
      o.x = e1.x*inv.x; o.y = e1.y*inv.y; o.z = e1.z*inv.z; o.w = e1.w*inv.w; sc4[n*64+l+16] = o;
      o.x = e2.x*inv.x; o.y = e2.y*inv.y; o.z = e2.z*inv.z; o.w = e2.w*inv.w; sc4[n*64+l+32] = o;
      o.x = e3.x*inv.x; o.y = e3.y*inv.y; o.z = e3.z*inv.z; o.w = e3.w*inv.w; sc4[n*64+l+48] = o;
    }
    __syncthreads();
    // PV
    {
      const int n = tid >> 4;
      float4 o; o.x = 0.f; o.y = 0.f; o.z = 0.f; o.w = 0.f;
      for(int nb = 0; nb < 64; nb++){
        const int ci = cidx[nb];
        if(ci >= 0){
          const float vv = vcb[ci + tid];
          const float4 pr = sc4[n*64 + nb];
          o.x += pr.x*vv; o.y += pr.y*vv; o.z += pr.z*vv; o.w += pr.w*vv;
        }
      }
      if(cell == 0) oA = o; else oB = o;
    }
    __syncthreads();   // protect sc4 reuse / next phase
  }
  aoA[tid] = oA; aoB[tid] = oB;
  __syncthreads();

  // ---- proj + ls1*res ----
  float xh[8];
  {
    const float bp = proj_b[tid];
    float acc[8];
    #pragma unroll
    for(int r = 0; r < 8; r++) acc[r] = bp;
    #pragma unroll 4
    for(int c = 0; c < 128; c++){
      const float w = projT[c*128 + tid];
      const float4 a = aoA[c], bb = aoB[c];
      acc[0] += a.x*w;  acc[1] += a.y*w;  acc[2] += a.z*w;  acc[3] += a.w*w;
      acc[4] += bb.x*w; acc[5] += bb.y*w; acc[6] += bb.z*w; acc[7] += bb.w*w;
    }
    const float l1 = ls1[tid];
    #pragma unroll
    for(int r = 0; r < 8; r++) xh[r] = xv[r] + l1*acc[r];
  }

  // ---- LN2 ----
  #pragma unroll
  for(int r = 0; r < 8; r++) v[r] = xh[r];
  gsum8(v, red);
  float c2[8], s2a[8];
  #pragma unroll
  for(int r = 0; r < 8; r++){ c2[r] = xh[r] - v[r]*(1.f/128.f); s2a[r] = c2[r]*c2[r]; }
  gsum8(s2a, red);
  {
    const float g = n2g[tid], be = n2b[tid];
    float4 a, bb;
    a.x  = c2[0]*rsqrtf(s2a[0]*(1.f/128.f)+1e-6f)*g + be;
    a.y  = c2[1]*rsqrtf(s2a[1]*(1.f/128.f)+1e-6f)*g + be;
    a.z  = c2[2]*rsqrtf(s2a[2]*(1.f/128.f)+1e-6f)*g + be;
    a.w  = c2[3]*rsqrtf(s2a[3]*(1.f/128.f)+1e-6f)*g + be;
    bb.x = c2[4]*rsqrtf(s2a[4]*(1.f/128.f)+1e-6f)*g + be;
    bb.y = c2[5]*rsqrtf(s2a[5]*(1.f/128.f)+1e-6f)*g + be;
    bb.z = c2[6]*rsqrtf(s2a[6]*(1.f/128.f)+1e-6f)*g + be;
    bb.w = c2[7]*rsqrtf(s2a[7]*(1.f/128.f)+1e-6f)*g + be;
    xnA[tid] = a; xnB[tid] = bb;
  }
  __syncthreads();

  // ---- fc1 + midLN + gelu ----
  float hv0[8], hv1[8];
  {
    const float b0 = fc1_b[tid];
    const float b1 = (tid < 42) ? fc1_b[tid + 128] : 0.f;
    #pragma unroll
    for(int r = 0; r < 8; r++){ hv0[r] = b0; hv1[r] = b1; }
    #pragma unroll 2
    for(int c = 0; c < 128; c++){
      const float4 xa = xnA[c], xb = xnB[c];
      const float w0 = fc1T[c*170 + tid];
      hv0[0] += xa.x*w0; hv0[1] += xa.y*w0; hv0[2] += xa.z*w0; hv0[3] += xa.w*w0;
      hv0[4] += xb.x*w0; hv0[5] += xb.y*w0; hv0[6] += xb.z*w0; hv0[7] += xb.w*w0;
      if(tid < 42){
        const float w1 = fc1T[c*170 + tid + 128];
        hv1[0] += xa.x*w1; hv1[1] += xa.y*w1; hv1[2] += xa.z*w1; hv1[3] += xa.w*w1;
        hv1[4] += xb.x*w1; hv1[5] += xb.y*w1; hv1[6] += xb.z*w1; hv1[7] += xb.w*w1;
      }
    }
    if(tid >= 42){
      #pragma unroll
      for(int r = 0; r < 8; r++) hv1[r] = 0.f;
    }
  }
  #pragma unroll
  for(int r = 0; r < 8; r++) v[r] = hv0[r] + hv1[r];
  gsum8(v, red);
  float d0[8], d1[8], ssq[8];
  #pragma unroll
  for(int r = 0; r < 8; r++){
    const float hmu = v[r]*(1.f/170.f);
    d0[r] = hv0[r] - hmu;
    d1[r] = (tid < 42) ? (hv1[r] - hmu) : 0.f;
    ssq[r] = d0[r]*d0[r] + d1[r]*d1[r];
  }
  gsum8(ssq, red);
  {
    const float kA = 0.7978845608028654f, kB = 0.044715f;
    float hrs[8];
    #pragma unroll
    for(int r = 0; r < 8; r++) hrs[r] = rsqrtf(ssq[r]*(1.f/170.f) + 1e-6f);
    {
      const float g = mg[tid], be = mb[tid];
      float4 a, bb;
      float t;
      t = d0[0]*hrs[0]*g + be; a.x  = 0.5f*t*(1.f + tanhf(kA*(t + kB*t*t*t)));
      t = d0[1]*hrs[1]*g + be; a.y  = 0.5f*t*(1.f + tanhf(kA*(t + kB*t*t*t)));
      t = d0[2]*hrs[2]*g + be; a.z  = 0.5f*t*(1.f + tanhf(kA*(t + kB*t*t*t)));
      t = d0[3]*hrs[3]*g + be; a.w  = 0.5f*t*(1.f + tanhf(kA*(t + kB*t*t*t)));
      t = d0[4]*hrs[4]*g + be; bb.x = 0.5f*t*(1.f + tanhf(kA*(t + kB*t*t*t)));
      t = d0[5]*hrs[5]*g + be; bb.y = 0.5f*t*(1.f + tanhf(kA*(t + kB*t*t*t)));
      t = d0[6]*hrs[6]*g + be; bb.z = 0.5f*t*(1.f + tanhf(kA*(t + kB*t*t*t)));
      t = d0[7]*hrs[7]*g + be; bb.w = 0.5f*t*(1.f + tanhf(kA*(t + kB*t*t*t)));
      hsA[tid] = a; hsB[tid] = bb;
    }
    if(tid < 42){
      const float g = mg[tid + 128], be = mb[tid + 128];
      float4 a, bb;
      float t;
      t = d1[0]*hrs[0]*g + be; a.x  = 0.5f*t*(1.f + tanhf(kA*(t + kB*t*t*t)));
      t = d1[1]*hrs[1]*g + be; a.y  = 0.5f*t*(1.f + tanhf(kA*(t + kB*t*t*t)));
      t = d1[2]*hrs[2]*g + be; a.z  = 0.5f*t*(1.f + tanhf(kA*(t + kB*t*t*t)));
      t = d1[3]*hrs[3]*g + be; a.w  = 0.5f*t*(1.f + tanhf(kA*(t + kB*t*t*t)));
      t = d1[4]*hrs[4]*g + be; bb.x = 0.5f*t*(1.f + tanhf(kA*(t + kB*t*t*t)));
      t = d1[5]*hrs[5]*g + be; bb.y = 0.5f*t*(1.f + tanhf(kA*(t + kB*t*t*t)));
      t = d1[6]*hrs[6]*g + be; bb.z = 0.5f*t*(1.f + tanhf(kA*(t + kB*t*t*t)));
      t = d1[7]*hrs[7]*g + be; bb.w = 0.5f*t*(1.f + tanhf(kA*(t + kB*t*t*t)));
      hsA[tid + 128] = a; hsB[tid + 128] = bb;
    }
  }
  __syncthreads();

  // ---- fc2 + ls2*res -> xt ----
  {
    const float bf = fc2_b[tid];
    float acc[8];
    #pragma unroll
    for(int r = 0; r < 8; r++) acc[r] = bf;
    #pragma unroll 2
    for(int j = 0; j < 170; j++){
      const float w = fc2T[j*128 + tid];
      const float4 ha = hsA[j], hb = hsB[j];
      acc[0] += ha.x*w; acc[1] += ha.y*w; acc[2] += ha.z*w; acc[3] += ha.w*w;
      acc[4] += hb.x*w; acc[5] += hb.y*w; acc[6] += hb.z*w; acc[7] += hb.w*w;
    }
    const float l2 = ls2[tid];
    #pragma unroll
    for(int r = 0; r < 8; r++)
      xt_out[p[r] + tid] = xh[r] + l2*acc[r];
  }
}

// ---- K4: tiled transpose xt (B,HW,C) -> out (B,C,H,W) ----
__global__ void k_tout(const float* __restrict__ xt, float* __restrict__ out){
  __shared__ float tile[32][33];
  const int b = blockIdx.z;
  const int pb = blockIdx.x * 32;
  const int cb = blockIdx.y * 32;
  const int tx = threadIdx.x, ty = threadIdx.y;
  #pragma unroll
  for(int r = 0; r < 32; r += 8)
    tile[ty+r][tx] = xt[(size_t)((b<<14) + pb + ty + r)*128 + cb + tx];
  __syncthreads();
  #pragma unroll
  for(int r = 0; r < 32; r += 8)
    out[(size_t)(b*128 + cb + ty + r)*16384 + pb + tx] = tile[tx][ty+r];
}

extern "C" void kernel_launch(void* const* d_in, const int* in_sizes, int n_in,
                              void* d_out, int out_size, void* d_ws, size_t ws_size,
                              hipStream_t stream){
  const float* x      = (const float*)d_in[0];
  const float* qkv_w  = (const float*)d_in[1];
  const float* qkv_b  = (const float*)d_in[2];
  const float* qg     = (const float*)d_in[3];
  const float* qb     = (const float*)d_in[4];
  const float* kg     = (const float*)d_in[5];
  const float* kb     = (const float*)d_in[6];
  const float* proj_w = (const float*)d_in[7];
  const float* proj_b = (const float*)d_in[8];
  const float* n1g    = (const float*)d_in[9];
  const float* n1b    = (const float*)d_in[10];
  const float* n2g    = (const float*)d_in[11];
  const float* n2b    = (const float*)d_in[12];
  const float* ls1    = (const float*)d_in[13];
  const float* ls2    = (const float*)d_in[14];
  const float* fc1_w  = (const float*)d_in[15];
  const float* fc1_b  = (const float*)d_in[16];
  const float* mg     = (const float*)d_in[17];
  const float* mb     = (const float*)d_in[18];
  const float* fc2_w  = (const float*)d_in[19];
  const float* fc2_b  = (const float*)d_in[20];

  float* ws   = (float*)d_ws;
  float* xt   = ws;
  float* kcb  = ws + 4194304;
  float* vcb  = ws + 5242880;
  float* qkvT = ws + 6291456;
  float* projT= ws + 6340608;
  float* fc1T = ws + 6356992;
  float* fc2T = ws + 6378752;

  dim3 tgrid(512, 4, 2), tblk(32, 8);
  k_tin <<<tgrid, tblk, 0, stream>>>(x, xt);
  k_wt  <<<426, 256, 0, stream>>>(qkv_w, proj_w, fc1_w, fc2_w, qkvT, projT, fc1T, fc2T);
  k_kv  <<<1024, 256, 0, stream>>>(xt, qkvT, qkv_b, kg, kb, n1g, n1b, kcb, vcb);
  k_cell<<<4096, 128, 0, stream>>>(xt, qkvT, qkv_b, qg, qb, n1g, n1b,
                                   projT, proj_b, ls1, ls2, n2g, n2b,
                                   fc1T, fc1_b, mg, mb, fc2T, fc2_b,
                                   kcb, vcb, xt);
  k_tout<<<tgrid, tblk, 0, stream>>>(xt, (float*)d_out);
}

// Round 9
// 319.274 us; speedup vs baseline: 6.9502x; 1.3149x over previous
//
#include <hip/hip_runtime.h>
#include <hip/hip_bf16.h>

typedef __hip_bfloat16 BF;
typedef __attribute__((ext_vector_type(8))) short bf16x8;
typedef __attribute__((ext_vector_type(4))) float f32x4;

// B=2, C=128, H=W=128, K=8, STRIDE=2, DIL=2, NH=8, dh=16, HID=170, Hc=Wc=64
// fp32 in / fp32 out. MFMA (bf16 inputs, fp32 acc) for the dense GEMMs.
// ws (floats): xt[0,4194304) kcb[+1048576) vcb[+1048576) ; packs (bf16) at 6291456:
//   packQ 16384, packK 16384, packV 16384, packP 16384, packF1 22528, packF2 24576
//   = 112640 bf16 = 56320 floats -> end 6347776 floats (25.4 MB)

__device__ __forceinline__ void gsum8(float v[8], float* red){
  #pragma unroll
  for(int s = 1; s < 64; s <<= 1){
    #pragma unroll
    for(int i = 0; i < 8; i++) v[i] += __shfl_xor(v[i], s);
  }
  const int wid = threadIdx.x >> 6;
  __syncthreads();
  if((threadIdx.x & 63) == 0){
    #pragma unroll
    for(int i = 0; i < 8; i++) red[wid*8 + i] = v[i];
  }
  __syncthreads();
  #pragma unroll
  for(int i = 0; i < 8; i++) v[i] = red[i] + red[8 + i];
}

// Row-stat reduction for C-layout accumulators: s1/s2 are per-reg partials over
// this lane's cols; result = totals over both waves' cols for row (lane>>4)*4+r.
__device__ __forceinline__ void rowred(float s1[4], float s2[4], float* red,
                                       int wave, int lane){
  #pragma unroll
  for(int m = 1; m < 16; m <<= 1){
    #pragma unroll
    for(int r = 0; r < 4; r++){ s1[r] += __shfl_xor(s1[r], m); s2[r] += __shfl_xor(s2[r], m); }
  }
  const int q4 = lane >> 4;
  __syncthreads();
  if((lane & 15) == 0){
    #pragma unroll
    for(int r = 0; r < 4; r++){
      red[wave*32 + q4*4 + r]      = s1[r];
      red[wave*32 + 16 + q4*4 + r] = s2[r];
    }
  }
  __syncthreads();
  #pragma unroll
  for(int r = 0; r < 4; r++){
    s1[r] = red[q4*4 + r]      + red[32 + q4*4 + r];
    s2[r] = red[16 + q4*4 + r] + red[48 + q4*4 + r];
  }
}

// ---- K0: tiled transpose x (B,C,H,W) -> xt (B,HW,C) ----
__global__ void k_tin(const float* __restrict__ x, float* __restrict__ xt){
  __shared__ float tile[32][33];
  const int b = blockIdx.z;
  const int pb = blockIdx.x * 32;
  const int cb = blockIdx.y * 32;
  const int tx = threadIdx.x, ty = threadIdx.y;
  #pragma unroll
  for(int r = 0; r < 32; r += 8)
    tile[ty+r][tx] = x[(size_t)(b*128 + cb+ty+r)*16384 + pb + tx];
  __syncthreads();
  #pragma unroll
  for(int r = 0; r < 32; r += 8)
    xt[(size_t)((b<<14) + pb + ty + r)*128 + cb + tx] = tile[tx][ty+r];
}

// ---- K1: pack weights to MFMA-B fragment layout, bf16 ----
// pack[((s*N + n)*4 + q)*8 + j] = W[k = s*32 + q*8 + j][n]
__global__ void k_wt(const float* __restrict__ qkv_w, const float* __restrict__ proj_w,
                     const float* __restrict__ fc1_w, const float* __restrict__ fc2_w,
                     BF* __restrict__ pk){
  const int idx = blockIdx.x * 256 + threadIdx.x;
  if(idx >= 112640) return;
  float val;
  if(idx < 49152){                 // Q,K,V (N=128,S=4) from qkv_w[(reg*128+n)*128+k]
    const int reg = idx >> 14, l = idx & 16383;
    const int j = l & 7, q = (l>>3)&3, n = (l>>5)&127, s = l>>12;
    val = qkv_w[(reg*128 + n)*128 + (s*32 + q*8 + j)];
  } else if(idx < 65536){          // proj (N=128,S=4)
    const int l = idx - 49152;
    const int j = l&7, q=(l>>3)&3, n=(l>>5)&127, s=l>>12;
    val = proj_w[n*128 + (s*32+q*8+j)];
  } else if(idx < 88064){          // fc1 (N=176 pad, S=4)
    const int l = idx - 65536;
    const int j = l&7, q=(l>>3)&3, rem = l>>5;
    const int n = rem % 176, s = rem / 176;
    const int k = s*32+q*8+j;
    val = (n < 170) ? fc1_w[n*128 + k] : 0.f;
  } else {                         // fc2 (N=128, S=6, K pad 170->192)
    const int l = idx - 88064;
    const int j = l&7, q=(l>>3)&3, n=(l>>5)&127, s=l>>12;
    const int k = s*32+q*8+j;
    val = (k < 170) ? fc2_w[n*170 + k] : 0.f;
  }
  pk[idx] = __float2bfloat16(val);
}

// ---- K2: coarse k,v via MFMA: 8 coarse px/block ----
__global__ void __launch_bounds__(128)
k_kv(const float* __restrict__ xt,
     const BF* __restrict__ packK, const BF* __restrict__ packV,
     const float* __restrict__ qkv_b,
     const float* __restrict__ kg, const float* __restrict__ kb,
     const float* __restrict__ n1g, const float* __restrict__ n1b,
     float* __restrict__ kcb, float* __restrict__ vcb){
  __shared__ BF Abuf[16*128];
  __shared__ float red[64];
  const int tid = threadIdx.x, wave = tid>>6, lane = tid&63;
  const int l15 = lane & 15, q4 = lane >> 4;
  { uint32_t* az = (uint32_t*)Abuf; for(int i = tid; i < 1024; i += 128) az[i] = 0; }
  const int bx = blockIdx.x;
  size_t prow[8];
  float xv[8];
  #pragma unroll
  for(int r = 0; r < 8; r++){
    const int cp = bx*8 + r;
    const int b = cp>>12, rm = cp&4095, ic = rm>>6, jcc = rm&63;
    prow[r] = ((size_t)(b*16384 + (2*ic)*128 + 2*jcc))*128;
    xv[r] = xt[prow[r] + tid];
  }
  float v[8];
  #pragma unroll
  for(int r = 0; r < 8; r++) v[r] = xv[r];
  gsum8(v, red);
  float xc[8], sq[8];
  #pragma unroll
  for(int r = 0; r < 8; r++){ xc[r] = xv[r] - v[r]*(1.f/128.f); sq[r] = xc[r]*xc[r]; }
  gsum8(sq, red);
  {
    const float g = n1g[tid], be = n1b[tid];
    #pragma unroll
    for(int r = 0; r < 8; r++)
      Abuf[r*128 + tid] = __float2bfloat16(xc[r]*rsqrtf(sq[r]*(1.f/128.f)+1e-6f)*g + be);
  }
  __syncthreads();
  bf16x8 af[4];
  #pragma unroll
  for(int s = 0; s < 4; s++) af[s] = *(const bf16x8*)&Abuf[l15*128 + s*32 + q4*8];

  // ---- k GEMM ----
  f32x4 acc[4];
  #pragma unroll
  for(int nt = 0; nt < 4; nt++){ acc[nt][0]=0.f; acc[nt][1]=0.f; acc[nt][2]=0.f; acc[nt][3]=0.f; }
  #pragma unroll
  for(int nt = 0; nt < 4; nt++){
    const int n = (wave*4+nt)*16 + l15;
    #pragma unroll
    for(int s = 0; s < 4; s++){
      bf16x8 bf = *(const bf16x8*)&packK[((s*128 + n)*4 + q4)*8];
      acc[nt] = __builtin_amdgcn_mfma_f32_16x16x32_bf16(af[s], bf, acc[nt], 0,0,0);
    }
  }
  float s1[4], s2[4], colb[4];
  #pragma unroll
  for(int r = 0; r < 4; r++){ s1[r]=0.f; s2[r]=0.f; }
  #pragma unroll
  for(int nt = 0; nt < 4; nt++){
    colb[nt] = qkv_b[128 + (wave*4+nt)*16 + l15];
    #pragma unroll
    for(int r = 0; r < 4; r++){
      const float vv = acc[nt][r] + colb[nt];
      acc[nt][r] = vv; s1[r] += vv; s2[r] += vv*vv;
    }
  }
  rowred(s1, s2, red, wave, lane);
  #pragma unroll
  for(int nt = 0; nt < 4; nt++){
    const int col = (wave*4+nt)*16 + l15;
    const float g = kg[col], be = kb[col];
    #pragma unroll
    for(int r = 0; r < 4; r++){
      const int row = q4*4 + r;
      if(row < 8){
        const float mu = s1[r]*(1.f/128.f);
        const float var = s2[r]*(1.f/128.f) - mu*mu;
        kcb[(size_t)(bx*8+row)*128 + col] = (acc[nt][r]-mu)*rsqrtf(var+1e-6f)*g + be;
      }
    }
  }
  // ---- v GEMM ----
  #pragma unroll
  for(int nt = 0; nt < 4; nt++){ acc[nt][0]=0.f; acc[nt][1]=0.f; acc[nt][2]=0.f; acc[nt][3]=0.f; }
  #pragma unroll
  for(int nt = 0; nt < 4; nt++){
    const int n = (wave*4+nt)*16 + l15;
    #pragma unroll
    for(int s = 0; s < 4; s++){
      bf16x8 bf = *(const bf16x8*)&packV[((s*128 + n)*4 + q4)*8];
      acc[nt] = __builtin_amdgcn_mfma_f32_16x16x32_bf16(af[s], bf, acc[nt], 0,0,0);
    }
  }
  #pragma unroll
  for(int nt = 0; nt < 4; nt++){
    const int col = (wave*4+nt)*16 + l15;
    const float bv = qkv_b[256 + col];
    #pragma unroll
    for(int r = 0; r < 4; r++){
      const int row = q4*4 + r;
      if(row < 8) vcb[(size_t)(bx*8+row)*128 + col] = acc[nt][r] + bv;
    }
  }
}

// ---- K3: fused per-2-cells (8 pixels) block, MFMA GEMMs ----
__global__ void __launch_bounds__(128)
k_cell(const float* __restrict__ xt_in,
       const BF* __restrict__ packQ, const BF* __restrict__ packP,
       const BF* __restrict__ packF1, const BF* __restrict__ packF2,
       const float* __restrict__ qkv_b,
       const float* __restrict__ qg, const float* __restrict__ qb,
       const float* __restrict__ n1g, const float* __restrict__ n1b,
       const float* __restrict__ proj_b,
       const float* __restrict__ ls1, const float* __restrict__ ls2,
       const float* __restrict__ n2g, const float* __restrict__ n2b,
       const float* __restrict__ fc1_b,
       const float* __restrict__ mg, const float* __restrict__ mb,
       const float* __restrict__ fc2_b,
       const float* __restrict__ kcb, const float* __restrict__ vcb,
       float* __restrict__ xt_out){
  __shared__ BF Abuf[16*192];          // A staging [m][k], k-stride 192
  __shared__ float xvL[8*128];
  __shared__ float4 qnA[128], qnB[128];
  __shared__ float4 sc4[512];
  __shared__ int cidxA[64], cidxB[64];
  __shared__ float red[64];
  const int tid = threadIdx.x, wave = tid>>6, lane = tid&63;
  const int l15 = lane & 15, q4 = lane >> 4;
  { uint32_t* az = (uint32_t*)Abuf; for(int i = tid; i < 1536; i += 128) az[i] = 0; }

  const int bx = blockIdx.x;
  const int b = bx >> 11, rem = bx & 2047, ip = rem >> 6, jc = rem & 63;
  const int icA = 2*ip, icB = 2*ip + 1;
  const size_t base = (size_t)b * 16384 * 128;
  size_t p[8];
  {
    const int h0 = 4*ip;
    p[0] = base + ((size_t)(h0*128     + 2*jc    ))*128;
    p[1] = base + ((size_t)(h0*128     + 2*jc + 1))*128;
    p[2] = base + ((size_t)((h0+1)*128 + 2*jc    ))*128;
    p[3] = base + ((size_t)((h0+1)*128 + 2*jc + 1))*128;
    p[4] = base + ((size_t)((h0+2)*128 + 2*jc    ))*128;
    p[5] = base + ((size_t)((h0+2)*128 + 2*jc + 1))*128;
    p[6] = base + ((size_t)((h0+3)*128 + 2*jc    ))*128;
    p[7] = base + ((size_t)((h0+3)*128 + 2*jc + 1))*128;
  }
  float xv[8];
  #pragma unroll
  for(int r = 0; r < 8; r++){ xv[r] = xt_in[p[r] + tid]; xvL[r*128 + tid] = xv[r]; }

  // ---- LN1 ----
  float v[8];
  #pragma unroll
  for(int r = 0; r < 8; r++) v[r] = xv[r];
  gsum8(v, red);
  float xc[8], sq[8];
  #pragma unroll
  for(int r = 0; r < 8; r++){ xc[r] = xv[r] - v[r]*(1.f/128.f); sq[r] = xc[r]*xc[r]; }
  gsum8(sq, red);
  {
    const float g = n1g[tid], be = n1b[tid];
    #pragma unroll
    for(int r = 0; r < 8; r++)
      Abuf[r*192 + tid] = __float2bfloat16(xc[r]*rsqrtf(sq[r]*(1.f/128.f)+1e-6f)*g + be);
  }
  if(tid < 64){
    const int i = tid >> 3, j = tid & 7;
    const int rj = jc + 2*j - 8;
    const bool vj = (rj >= 0) && (rj < 64);
    const int riA = icA + 2*i - 8, riB = icB + 2*i - 8;
    cidxA[tid] = (vj && riA >= 0 && riA < 64) ? ((b*4096 + riA*64 + rj)*128) : -1;
    cidxB[tid] = (vj && riB >= 0 && riB < 64) ? ((b*4096 + riB*64 + rj)*128) : -1;
  }
  __syncthreads();

  // ---- q GEMM + q-LN -> qnA/qnB ----
  {
    bf16x8 af[4];
    #pragma unroll
    for(int s = 0; s < 4; s++) af[s] = *(const bf16x8*)&Abuf[l15*192 + s*32 + q4*8];
    f32x4 acc[4];
    #pragma unroll
    for(int nt = 0; nt < 4; nt++){ acc[nt][0]=0.f; acc[nt][1]=0.f; acc[nt][2]=0.f; acc[nt][3]=0.f; }
    #pragma unroll
    for(int nt = 0; nt < 4; nt++){
      const int n = (wave*4+nt)*16 + l15;
      #pragma unroll
      for(int s = 0; s < 4; s++){
        bf16x8 bf = *(const bf16x8*)&packQ[((s*128 + n)*4 + q4)*8];
        acc[nt] = __builtin_amdgcn_mfma_f32_16x16x32_bf16(af[s], bf, acc[nt], 0,0,0);
      }
    }
    float s1[4], s2[4];
    #pragma unroll
    for(int r = 0; r < 4; r++){ s1[r]=0.f; s2[r]=0.f; }
    #pragma unroll
    for(int nt = 0; nt < 4; nt++){
      const float cb2 = qkv_b[(wave*4+nt)*16 + l15];
      #pragma unroll
      for(int r = 0; r < 4; r++){
        const float vv = acc[nt][r] + cb2;
        acc[nt][r] = vv; s1[r] += vv; s2[r] += vv*vv;
      }
    }
    rowred(s1, s2, red, wave, lane);
    if(q4 < 2){
      float mu[4], rs[4];
      #pragma unroll
      for(int r = 0; r < 4; r++){
        mu[r] = s1[r]*(1.f/128.f);
        rs[r] = rsqrtf(s2[r]*(1.f/128.f) - mu[r]*mu[r] + 1e-6f);
      }
      #pragma unroll
      for(int nt = 0; nt < 4; nt++){
        const int col = (wave*4+nt)*16 + l15;
        const float g = qg[col], be = qb[col];
        float4 t;
        t.x = (acc[nt][0]-mu[0])*rs[0]*g + be;
        t.y = (acc[nt][1]-mu[1])*rs[1]*g + be;
        t.z = (acc[nt][2]-mu[2])*rs[2]*g + be;
        t.w = (acc[nt][3]-mu[3])*rs[3]*g + be;
        if(q4 == 0) qnA[col] = t; else qnB[col] = t;
      }
    }
  }
  __syncthreads();

  // ---- attention (R8-verified), output -> registers oA,oB ----
  float4 oA, oB;
  for(int cell = 0; cell < 2; cell++){
    const int* cidx = cell ? cidxB : cidxA;
    #pragma unroll
    for(int rep = 0; rep < 4; rep++){
      const int idx = rep*128 + tid;
      const int n = idx >> 6, nb = idx & 63;
      const int ci = cidx[nb];
      float4 s; s.x = -1e30f; s.y = -1e30f; s.z = -1e30f; s.w = -1e30f;
      if(ci >= 0){
        const float* kp = kcb + ci + n*16;
        float4 a; a.x = 0.f; a.y = 0.f; a.z = 0.f; a.w = 0.f;
        #pragma unroll
        for(int d = 0; d < 16; d++){
          const float kvv = kp[d];
          const float4 qq = cell ? qnB[n*16 + d] : qnA[n*16 + d];
          a.x += qq.x*kvv; a.y += qq.y*kvv; a.z += qq.z*kvv; a.w += qq.w*kvv;
        }
        s.x = a.x*0.25f; s.y = a.y*0.25f; s.z = a.z*0.25f; s.w = a.w*0.25f;
      }
      sc4[idx] = s;
    }
    __syncthreads();
    {
      const int n = tid >> 4, l = tid & 15;
      float4 s0 = sc4[n*64 + l], s1 = sc4[n*64 + l + 16];
      float4 s2 = sc4[n*64 + l + 32], s3 = sc4[n*64 + l + 48];
      float4 m;
      m.x = fmaxf(fmaxf(s0.x,s1.x), fmaxf(s2.x,s3.x));
      m.y = fmaxf(fmaxf(s0.y,s1.y), fmaxf(s2.y,s3.y));
      m.z = fmaxf(fmaxf(s0.z,s1.z), fmaxf(s2.z,s3.z));
      m.w = fmaxf(fmaxf(s0.w,s1.w), fmaxf(s2.w,s3.w));
      #pragma unroll
      for(int sft = 1; sft < 16; sft <<= 1){
        m.x = fmaxf(m.x, __shfl_xor(m.x, sft));
        m.y = fmaxf(m.y, __shfl_xor(m.y, sft));
        m.z = fmaxf(m.z, __shfl_xor(m.z, sft));
        m.w = fmaxf(m.w, __shfl_xor(m.w, sft));
      }
      float4 e0, e1, e2, e3, es;
      e0.x = __expf(s0.x-m.x); e0.y = __expf(s0.y-m.y); e0.z = __expf(s0.z-m.z); e0.w = __expf(s0.w-m.w);
      e1.x = __expf(s1.x-m.x); e1.y = __expf(s1.y-m.y); e1.z = __expf(s1.z-m.z); e1.w = __expf(s1.w-m.w);
      e2.x = __expf(s2.x-m.x); e2.y = __expf(s2.y-m.y); e2.z = __expf(s2.z-m.z); e2.w = __expf(s2.w-m.w);
      e3.x = __expf(s3.x-m.x); e3.y = __expf(s3.y-m.y); e3.z = __expf(s3.z-m.z); e3.w = __expf(s3.w-m.w);
      es.x = e0.x+e1.x+e2.x+e3.x; es.y = e0.y+e1.y+e2.y+e3.y;
      es.z = e0.z+e1.z+e2.z+e3.z; es.w = e0.w+e1.w+e2.w+e3.w;
      #pragma unroll
      for(int sft = 1; sft < 16; sft <<= 1){
        es.x += __shfl_xor(es.x, sft); es.y += __shfl_xor(es.y, sft);
        es.z += __shfl_xor(es.z, sft); es.w += __shfl_xor(es.w, sft);
      }
      float4 inv; inv.x = 1.f/es.x; inv.y = 1.f/es.y; inv.z = 1.f/es.z; inv.w = 1.f/es.w;
      float4 o;
      o.x = e0.x*inv.x; o.y = e0.y*inv.y; o.z = e0.z*inv.z; o.w = e0.w*inv.w; sc4[n*64+l]    = o;
      o.x = e1.x*inv.x; o.y = e1.y*inv.y; o.z = e1.z*inv.z; o.w = e1.w*inv.w; sc4[n*64+l+16] = o;
      o.x = e2.x*inv.x; o.y = e2.y*inv.y; o.z = e2.z*inv.z; o.w = e2.w*inv.w; sc4[n*64+l+32] = o;
      o.x = e3.x*inv.x; o.y = e3.y*inv.y; o.z = e3.z*inv.z; o.w = e3.w*inv.w; sc4[n*64+l+48] = o;
    }
    __syncthreads();
    {
      const int n = tid >> 4;
      float4 o; o.x = 0.f; o.y = 0.f; o.z = 0.f; o.w = 0.f;
      for(int nb = 0; nb < 64; nb++){
        const int ci = cidx[nb];
        if(ci >= 0){
          const float vv = vcb[ci + tid];
          const float4 pr = sc4[n*64 + nb];
          o.x += pr.x*vv; o.y += pr.y*vv; o.z += pr.z*vv; o.w += pr.w*vv;
        }
      }
      if(cell == 0) oA = o; else oB = o;
    }
    __syncthreads();
  }
  // ao -> Abuf (A of proj)
  Abuf[0*192 + tid] = __float2bfloat16(oA.x);
  Abuf[1*192 + tid] = __float2bfloat16(oA.y);
  Abuf[2*192 + tid] = __float2bfloat16(oA.z);
  Abuf[3*192 + tid] = __float2bfloat16(oA.w);
  Abuf[4*192 + tid] = __float2bfloat16(oB.x);
  Abuf[5*192 + tid] = __float2bfloat16(oB.y);
  Abuf[6*192 + tid] = __float2bfloat16(oB.z);
  Abuf[7*192 + tid] = __float2bfloat16(oB.w);
  __syncthreads();

  // ---- proj GEMM + ls1*res -> xh (C-layout regs), LN2 -> Abuf ----
  float xh[4][4];
  {
    bf16x8 af[4];
    #pragma unroll
    for(int s = 0; s < 4; s++) af[s] = *(const bf16x8*)&Abuf[l15*192 + s*32 + q4*8];
    f32x4 acc[4];
    #pragma unroll
    for(int nt = 0; nt < 4; nt++){ acc[nt][0]=0.f; acc[nt][1]=0.f; acc[nt][2]=0.f; acc[nt][3]=0.f; }
    #pragma unroll
    for(int nt = 0; nt < 4; nt++){
      const int n = (wave*4+nt)*16 + l15;
      #pragma unroll
      for(int s = 0; s < 4; s++){
        bf16x8 bf = *(const bf16x8*)&packP[((s*128 + n)*4 + q4)*8];
        acc[nt] = __builtin_amdgcn_mfma_f32_16x16x32_bf16(af[s], bf, acc[nt], 0,0,0);
      }
    }
    float s1[4], s2[4];
    #pragma unroll
    for(int r = 0; r < 4; r++){ s1[r]=0.f; s2[r]=0.f; }
    #pragma unroll
    for(int nt = 0; nt < 4; nt++){
      const int col = (wave*4+nt)*16 + l15;
      const float bp = proj_b[col], l1 = ls1[col];
      #pragma unroll
      for(int r = 0; r < 4; r++){
        const int row = q4*4 + r;
        const float xvv = (row < 8) ? xvL[row*128 + col] : 0.f;
        const float hx = xvv + l1*(acc[nt][r] + bp);
        xh[nt][r] = hx; s1[r] += hx; s2[r] += hx*hx;
      }
    }
    rowred(s1, s2, red, wave, lane);
    #pragma unroll
    for(int nt = 0; nt < 4; nt++){
      const int col = (wave*4+nt)*16 + l15;
      const float g = n2g[col], be = n2b[col];
      #pragma unroll
      for(int r = 0; r < 4; r++){
        const int row = q4*4 + r;
        if(row < 8){
          const float mu = s1[r]*(1.f/128.f);
          const float var = s2[r]*(1.f/128.f) - mu*mu;
          Abuf[row*192 + col] =
            __float2bfloat16((xh[nt][r]-mu)*rsqrtf(var+1e-6f)*g + be);
        }
      }
    }
  }
  __syncthreads();

  // ---- fc1 GEMM (N=176) + midLN + gelu -> Abuf (A of fc2, K up to 170) ----
  {
    bf16x8 af[4];
    #pragma unroll
    for(int s = 0; s < 4; s++) af[s] = *(const bf16x8*)&Abuf[l15*192 + s*32 + q4*8];
    const int NT1 = wave ? 5 : 6;           // wave0 tiles 0..5, wave1 tiles 6..10
    f32x4 acc1[6];
    #pragma unroll
    for(int nt = 0; nt < 6; nt++){ acc1[nt][0]=0.f; acc1[nt][1]=0.f; acc1[nt][2]=0.f; acc1[nt][3]=0.f; }
    for(int nt = 0; nt < NT1; nt++){
      const int tI = wave ? (6 + nt) : nt;
      const int n = tI*16 + l15;
      #pragma unroll
      for(int s = 0; s < 4; s++){
        bf16x8 bf = *(const bf16x8*)&packF1[((s*176 + n)*4 + q4)*8];
        acc1[nt] = __builtin_amdgcn_mfma_f32_16x16x32_bf16(af[s], bf, acc1[nt], 0,0,0);
      }
    }
    float s1[4], s2[4];
    #pragma unroll
    for(int r = 0; r < 4; r++){ s1[r]=0.f; s2[r]=0.f; }
    for(int nt = 0; nt < NT1; nt++){
      const int tI = wave ? (6 + nt) : nt;
      const int col = tI*16 + l15;
      const float b1 = (col < 170) ? fc1_b[col] : 0.f;
      #pragma unroll
      for(int r = 0; r < 4; r++){
        const float vv = acc1[nt][r] + b1;
        acc1[nt][r] = vv; s1[r] += vv; s2[r] += vv*vv;
      }
    }
    rowred(s1, s2, red, wave, lane);
    const float kA = 0.7978845608028654f, kB = 0.044715f;
    for(int nt = 0; nt < NT1; nt++){
      const int tI = wave ? (6 + nt) : nt;
      const int col = tI*16 + l15;
      if(col < 170){
        const float g = mg[col], be = mb[col];
        #pragma unroll
        for(int r = 0; r < 4; r++){
          const int row = q4*4 + r;
          if(row < 8){
            const float mu = s1[r]*(1.f/170.f);
            const float var = s2[r]*(1.f/170.f) - mu*mu;
            const float hn = (acc1[nt][r]-mu)*rsqrtf(var+1e-6f)*g + be;
            const float gl = 0.5f*hn*(1.f + tanhf(kA*(hn + kB*hn*hn*hn)));
            Abuf[row*192 + col] = __float2bfloat16(gl);
          }
        }
      }
    }
  }
  __syncthreads();

  // ---- fc2 GEMM (K=192) + ls2*res -> xt ----
  {
    bf16x8 af[6];
    #pragma unroll
    for(int s = 0; s < 6; s++) af[s] = *(const bf16x8*)&Abuf[l15*192 + s*32 + q4*8];
    f32x4 acc[4];
    #pragma unroll
    for(int nt = 0; nt < 4; nt++){ acc[nt][0]=0.f; acc[nt][1]=0.f; acc[nt][2]=0.f; acc[nt][3]=0.f; }
    #pragma unroll
    for(int nt = 0; nt < 4; nt++){
      const int n = (wave*4+nt)*16 + l15;
      #pragma unroll
      for(int s = 0; s < 6; s++){
        bf16x8 bf = *(const bf16x8*)&packF2[((s*128 + n)*4 + q4)*8];
        acc[nt] = __builtin_amdgcn_mfma_f32_16x16x32_bf16(af[s], bf, acc[nt], 0,0,0);
      }
    }
    #pragma unroll
    for(int nt = 0; nt < 4; nt++){
      const int col = (wave*4+nt)*16 + l15;
      const float bf2 = fc2_b[col], l2 = ls2[col];
      #pragma unroll
      for(int r = 0; r < 4; r++){
        const int row = q4*4 + r;
        if(row < 8)
          xt_out[p[row] + col] = xh[nt][r] + l2*(acc[nt][r] + bf2);
      }
    }
  }
}

// ---- K4: tiled transpose xt (B,HW,C) -> out (B,C,H,W) ----
__global__ void k_tout(const float* __restrict__ xt, float* __restrict__ out){
  __shared__ float tile[32][33];
  const int b = blockIdx.z;
  const int pb = blockIdx.x * 32;
  const int cb = blockIdx.y * 32;
  const int tx = threadIdx.x, ty = threadIdx.y;
  #pragma unroll
  for(int r = 0; r < 32; r += 8)
    tile[ty+r][tx] = xt[(size_t)((b<<14) + pb + ty + r)*128 + cb + tx];
  __syncthreads();
  #pragma unroll
  for(int r = 0; r < 32; r += 8)
    out[(size_t)(b*128 + cb + ty + r)*16384 + pb + tx] = tile[tx][ty+r];
}

extern "C" void kernel_launch(void* const* d_in, const int* in_sizes, int n_in,
                              void* d_out, int out_size, void* d_ws, size_t ws_size,
                              hipStream_t stream){
  const float* x      = (const float*)d_in[0];
  const float* qkv_w  = (const float*)d_in[1];
  const float* qkv_b  = (const float*)d_in[2];
  const float* qg     = (const float*)d_in[3];
  const float* qb     = (const float*)d_in[4];
  const float* kg     = (const float*)d_in[5];
  const float* kb     = (const float*)d_in[6];
  const float* proj_w = (const float*)d_in[7];
  const float* proj_b = (const float*)d_in[8];
  const float* n1g    = (const float*)d_in[9];
  const float* n1b    = (const float*)d_in[10];
  const float* n2g    = (const float*)d_in[11];
  const float* n2b    = (const float*)d_in[12];
  const float* ls1    = (const float*)d_in[13];
  const float* ls2    = (const float*)d_in[14];
  const float* fc1_w  = (const float*)d_in[15];
  const float* fc1_b  = (const float*)d_in[16];
  const float* mg     = (const float*)d_in[17];
  const float* mb     = (const float*)d_in[18];
  const float* fc2_w  = (const float*)d_in[19];
  const float* fc2_b  = (const float*)d_in[20];

  float* ws  = (float*)d_ws;
  float* xt  = ws;
  float* kcb = ws + 4194304;
  float* vcb = ws + 5242880;
  BF* pk     = (BF*)(ws + 6291456);
  BF* packQ  = pk;
  BF* packK  = pk + 16384;
  BF* packV  = pk + 32768;
  BF* packP  = pk + 49152;
  BF* packF1 = pk + 65536;
  BF* packF2 = pk + 88064;

  dim3 tgrid(512, 4, 2), tblk(32, 8);
  k_tin <<<tgrid, tblk, 0, stream>>>(x, xt);
  k_wt  <<<440, 256, 0, stream>>>(qkv_w, proj_w, fc1_w, fc2_w, pk);
  k_kv  <<<1024, 128, 0, stream>>>(xt, packK, packV, qkv_b, kg, kb, n1g, n1b, kcb, vcb);
  k_cell<<<4096, 128, 0, stream>>>(xt, packQ, packP, packF1, packF2,
                                   qkv_b, qg, qb, n1g, n1b, proj_b, ls1, ls2,
                                   n2g, n2b, fc1_b, mg, mb, fc2_b,
                                   kcb, vcb, xt);
  k_tout<<<tgrid, tblk, 0, stream>>>(xt, (float*)d_out);
}